// Round 4
// baseline (276.133 us; speedup 1.0000x reference)
//
#include <hip/hip_runtime.h>
#include <math.h>

// mask[i][j] = (j < blk_end(i)) && (j != i),  blk_end = (i/n_nodes + 1)*n_nodes
// (equivalent to ((i>j) | same_block) & (i!=j))
//
// Pure HBM-write-bound: n=8192 -> 268 MB fp32 out, ~0 bytes read.
// Structure mirrors __amd_rocclr_fillBufferAligned (6.4-6.6 TB/s on this box):
// flat 1D grid-stride, 2048 blocks x 256 threads (8 blk/CU -> 32 waves/CU),
// one global_store_dwordx4 nt per iteration.

typedef float vfloat4 __attribute__((ext_vector_type(4)));

__global__ void __launch_bounds__(256)
Create_Mask_23871428231714_kernel(const int* __restrict__ n_nodes_p,
                                  float* __restrict__ out,
                                  int n, int log2n) {
    const int n_nodes = *n_nodes_p;
    // pow2 fast path for the per-thread row-block computation (n_nodes=64 here)
    const bool nn_pow2 = (n_nodes & (n_nodes - 1)) == 0;
    const int s = nn_pow2 ? (__ffs(n_nodes) - 1) : 0;

    const size_t nv = ((size_t)n * (size_t)n) >> 2;   // total float4s
    const size_t stride = (size_t)gridDim.x * blockDim.x;
    vfloat4* __restrict__ o = reinterpret_cast<vfloat4*>(out);

    for (size_t idx = (size_t)blockIdx.x * blockDim.x + threadIdx.x;
         idx < nv; idx += stride) {
        const size_t flat = idx << 2;                 // element index
        int i, j0;
        if (log2n >= 0) {                             // n power of two (8192)
            i  = (int)(flat >> log2n);
            j0 = (int)(flat & (size_t)(n - 1));
        } else {                                      // generic fallback
            i  = (int)(flat / (size_t)n);
            j0 = (int)(flat - (size_t)i * (size_t)n);
        }
        const int blk_end = nn_pow2 ? (((i >> s) + 1) << s)
                                    : ((i / n_nodes + 1) * n_nodes);
        vfloat4 val;
        val.x = ((j0     < blk_end) && (j0     != i)) ? 1.0f : 0.0f;
        val.y = ((j0 + 1 < blk_end) && (j0 + 1 != i)) ? 1.0f : 0.0f;
        val.z = ((j0 + 2 < blk_end) && (j0 + 2 != i)) ? 1.0f : 0.0f;
        val.w = ((j0 + 3 < blk_end) && (j0 + 3 != i)) ? 1.0f : 0.0f;
        __builtin_nontemporal_store(val, o + idx);    // global_store_dwordx4 ... nt
    }
}

extern "C" void kernel_launch(void* const* d_in, const int* in_sizes, int n_in,
                              void* d_out, int out_size, void* d_ws, size_t ws_size,
                              hipStream_t stream) {
    (void)in_sizes; (void)n_in; (void)d_ws; (void)ws_size;
    const int* n_nodes_p = (const int*)d_in[0];
    float* out = (float*)d_out;

    // out is n x n -> recover n on host (no device readback; graph-capture safe)
    const int n = (int)llround(sqrt((double)out_size));
    int log2n = -1;
    if ((n & (n - 1)) == 0) { log2n = 0; while ((1 << log2n) < n) ++log2n; }

    // 2048 blocks x 256 thr = 8 blocks/CU on 256 CUs (32 waves/CU), ~32 f4/thread
    const int grid = 2048;
    Create_Mask_23871428231714_kernel<<<dim3(grid, 1, 1), dim3(256, 1, 1), 0, stream>>>(
        n_nodes_p, out, n, log2n);
}

// Round 5
// 248.727 us; speedup vs baseline: 1.1102x; 1.1102x over previous
//
#include <hip/hip_runtime.h>
#include <math.h>

// mask[i][j] = (j < blk_end(i)) && (j != i),  blk_end = (i/n_nodes + 1)*n_nodes
// (equivalent to reference's ((i>j) | same_block) & (i!=j))
//
// Pure HBM-write-bound: n=8192 -> 268 MB fp32 out, ~0 bytes read.
// Empirically best structure (R1): one plain float4 store per thread, 2D grid,
// maximum parallelism, NO nontemporal hint, NO grid-stride loop.
// R3 (per-row loop + nt) and R4 (grid-stride + nt) both regressed.

__global__ void __launch_bounds__(256)
Create_Mask_23871428231714_kernel(const int* __restrict__ n_nodes_p,
                                  float* __restrict__ out, int n) {
    const int n_nodes = *n_nodes_p;                 // scalar, L2 broadcast
    const int i = blockIdx.y;                       // row
    const int j0 = (blockIdx.x * blockDim.x + threadIdx.x) << 2;

    // blk_end = (i/n_nodes + 1) * n_nodes; pow2 fast path (n_nodes=64)
    int blk_end;
    if ((n_nodes & (n_nodes - 1)) == 0) {
        const int s = __ffs(n_nodes) - 1;
        blk_end = ((i >> s) + 1) << s;
    } else {
        blk_end = (i / n_nodes + 1) * n_nodes;
    }

    float4 v;
    v.x = ((j0     < blk_end) && (j0     != i)) ? 1.0f : 0.0f;
    v.y = ((j0 + 1 < blk_end) && (j0 + 1 != i)) ? 1.0f : 0.0f;
    v.z = ((j0 + 2 < blk_end) && (j0 + 2 != i)) ? 1.0f : 0.0f;
    v.w = ((j0 + 3 < blk_end) && (j0 + 3 != i)) ? 1.0f : 0.0f;

    // n multiple of 4, j0 multiple of 4 -> 16B-aligned coalesced store
    *reinterpret_cast<float4*>(out + (size_t)i * (size_t)n + (size_t)j0) = v;
}

extern "C" void kernel_launch(void* const* d_in, const int* in_sizes, int n_in,
                              void* d_out, int out_size, void* d_ws, size_t ws_size,
                              hipStream_t stream) {
    (void)in_sizes; (void)n_in; (void)d_ws; (void)ws_size;
    const int* n_nodes_p = (const int*)d_in[0];
    float* out = (float*)d_out;

    // out is n x n -> recover n on host (no device readback; graph-capture safe)
    const int n = (int)llround(sqrt((double)out_size));

    const int block = 256;
    const int elems_per_block = block * 4;          // one float4 per thread
    dim3 grid((n + elems_per_block - 1) / elems_per_block, n, 1);
    Create_Mask_23871428231714_kernel<<<grid, dim3(block, 1, 1), 0, stream>>>(
        n_nodes_p, out, n);
}